// Round 6
// baseline (1358.765 us; speedup 1.0000x reference)
//
#include <hip/hip_runtime.h>
#include <hip/hip_fp16.h>
#include <math.h>

typedef unsigned short u16;
typedef float f32x4 __attribute__((ext_vector_type(4)));
typedef __bf16 bf16x8 __attribute__((ext_vector_type(8)));

__device__ __forceinline__ float b2f(u16 u) {
    union { unsigned int i; float f; } v; v.i = ((unsigned int)u) << 16; return v.f;
}
__device__ __forceinline__ u16 f2b(float f) {
    union { float f; unsigned int i; } v; v.f = f;
    unsigned int lsb = (v.i >> 16) & 1u;
    return (u16)((v.i + 0x7fffu + lsb) >> 16);   // RNE
}

// ---------------------------------------------------------------------------
// CSR build: counts -> block scan -> global scan -> fill
// ---------------------------------------------------------------------------
__global__ __launch_bounds__(256)
void k_count(const int* __restrict__ dst, int* __restrict__ cnt, int E)
{
    int e = blockIdx.x * 256 + threadIdx.x;
    if (e < E) atomicAdd(&cnt[dst[e]], 1);
}

__global__ __launch_bounds__(256)
void k_scan1(const int* __restrict__ cnt, int* __restrict__ rowptr,
             int* __restrict__ bsum, int N)
{
    __shared__ int s[256];
    int t = threadIdx.x, i = blockIdx.x * 256 + t;
    int v = (i < N) ? cnt[i] : 0;
    s[t] = v;
    __syncthreads();
#pragma unroll
    for (int off = 1; off < 256; off <<= 1) {
        int add = (t >= off) ? s[t - off] : 0;
        __syncthreads();
        s[t] += add;
        __syncthreads();
    }
    if (i < N) rowptr[i] = s[t] - v;
    if (t == 255) bsum[blockIdx.x] = s[255];
}

__global__ __launch_bounds__(256)
void k_scan2(const int* __restrict__ bsum, int* __restrict__ bscan, int nb)
{
    __shared__ int s[256];
    int t = threadIdx.x;
    int g[4], e[4];
    int base = t * 4;
#pragma unroll
    for (int j = 0; j < 4; ++j) g[j] = (base + j < nb) ? bsum[base + j] : 0;
    e[0] = 0; e[1] = g[0]; e[2] = g[0] + g[1]; e[3] = g[0] + g[1] + g[2];
    int tsum = e[3] + g[3];
    s[t] = tsum;
    __syncthreads();
#pragma unroll
    for (int off = 1; off < 256; off <<= 1) {
        int add = (t >= off) ? s[t - off] : 0;
        __syncthreads();
        s[t] += add;
        __syncthreads();
    }
    int texcl = s[t] - tsum;
#pragma unroll
    for (int j = 0; j < 4; ++j)
        if (base + j < nb) bscan[base + j] = texcl + e[j];
}

__global__ __launch_bounds__(256)
void k_scan3(int* __restrict__ rowptr, const int* __restrict__ bscan,
             int* __restrict__ cursor, int N)
{
    int i = blockIdx.x * 256 + threadIdx.x;
    if (i >= N) return;
    int r = rowptr[i] + bscan[i >> 8];
    rowptr[i] = r;
    cursor[i] = r;
}

__global__ __launch_bounds__(256)
void k_fill(const int* __restrict__ src, const int* __restrict__ dst,
            int* __restrict__ cursor, int* __restrict__ col, int E)
{
    int e = blockIdx.x * 256 + threadIdx.x;
    if (e >= E) return;
    int pos = atomicAdd(&cursor[dst[e]], 1);
    col[pos] = src[e];
}

// ---------------------------------------------------------------------------
// Gather aggregation: agg[i] = sum_{j in in(i)} relu?(h[col[j]]); f16 out.
// ---------------------------------------------------------------------------
template<int F, bool RELU, bool F32SRC>
__global__ __launch_bounds__(256)
void k_gather(const void* __restrict__ hsrc, const int* __restrict__ cnt,
              const int* __restrict__ rowptr, const int* __restrict__ col,
              __half* __restrict__ agg, int N)
{
    constexpr int CPE = F / 8;
    int tid = blockIdx.x * 256 + threadIdx.x;
    int node = tid / CPE, c = tid % CPE;
    if (node >= N) return;
    int n = cnt[node], rp = rowptr[node];
    float acc[8] = {0.f, 0.f, 0.f, 0.f, 0.f, 0.f, 0.f, 0.f};
    for (int j = 0; j < n; ++j) {
        int s = col[rp + j];
        if (F32SRC) {
            const float* p = (const float*)hsrc + (size_t)s * F + c * 8;
            float4 a = *(const float4*)p, b = *(const float4*)(p + 4);
            float xv[8] = {a.x, a.y, a.z, a.w, b.x, b.y, b.z, b.w};
#pragma unroll
            for (int i = 0; i < 8; ++i) acc[i] += RELU ? fmaxf(xv[i], 0.f) : xv[i];
        } else {
            u16 vs[8] __attribute__((aligned(16)));
            *(uint4*)vs = *(const uint4*)((const u16*)hsrc + (size_t)s * F + c * 8);
#pragma unroll
            for (int i = 0; i < 8; ++i) {
                float x = b2f(vs[i]);
                acc[i] += RELU ? fmaxf(x, 0.f) : x;
            }
        }
    }
    __half ob[8] __attribute__((aligned(16)));
#pragma unroll
    for (int i = 0; i < 8; ++i) ob[i] = __float2half(acc[i]);
    *(uint4*)(agg + (size_t)node * F + c * 8) = *(const uint4*)ob;
}

// transpose + f32->bf16 convert: out[n*K+k] = bf16(in[k*N+n])   (weights, tiny)
__global__ void k_T(const float* __restrict__ in, u16* __restrict__ out, int K, int N)
{
    int t = blockIdx.x * 256 + threadIdx.x;
    if (t >= K * N) return;
    int n = t / K, k = t % K;
    out[t] = f2b(in[k * N + n]);
}

// ---------------------------------------------------------------------------
// Fused GIN MLP v3: Hout(own 64 rows) = relu((relu?(A)+agg)@Wa+ba)@Wb+bb
// Block 64 rows x 256 cols, 4 waves in n; wave = 64x64, 4x4 frags of 16x16x32.
// LDS in MFMA-frag-blocked layout: every frag read is base + lane*16 bytes
// (conflict-free). As 4KB + Bs 16KB + Hs 32KB = 52KB -> 3 blocks/CU.
// Register prefetch double-buffering on the global->LDS staging.
// ---------------------------------------------------------------------------
template<int K, bool RELUIN, bool AF32>
__global__ __launch_bounds__(256, 3)
void k_gin(const void* Ain, const __half* __restrict__ agg,
           const u16* __restrict__ WaT, const float* __restrict__ ba,
           const u16* __restrict__ WbT, const float* __restrict__ bb,
           u16* Hout)
{
    __shared__ u16 As2[64 * 32];     //  4 KB : block (r,q): idx=(r*64+q*16+fm)*8
    __shared__ u16 Bs2[256 * 32];    // 16 KB : block (w,c,q): ((w*4+c)*64+q*16+fm)*8
    __shared__ u16 Hs2[64 * 256];    // 32 KB : ((kblk*4+r)*64+q*16+fm)*8 + elem

    const int tid = threadIdx.x, lane = tid & 63, wave = tid >> 6;
    const int bm0 = blockIdx.x * 64;
    const int lc = lane & 15, lr = (lane >> 4) * 4;
    const int cw0 = wave * 64;
    const int sr = tid >> 2, sc = tid & 3;                // A staging: row, k-chunk
    const int aidx = (((sr >> 4) * 64) + sc * 16 + (sr & 15)) * 8;
    const int brow = tid;                                  // B staging row
    const int bbase = ((((brow >> 6) * 4 + ((brow >> 4) & 3)) * 64) + (brow & 15)) * 8;

    uint4 pA;        // 8 bf16, ready to write
    uint4 pB[4];     // 4x 8 bf16

    auto prefA = [&](int k0) {
        const size_t aoff = (size_t)(bm0 + sr) * K + k0 + sc * 8;
        float av[8];
        if (AF32) {
            const float* p = (const float*)Ain + aoff;
            float4 a = *(const float4*)p, b = *(const float4*)(p + 4);
            av[0]=a.x; av[1]=a.y; av[2]=a.z; av[3]=a.w;
            av[4]=b.x; av[5]=b.y; av[6]=b.z; av[7]=b.w;
        } else {
            u16 hb[8] __attribute__((aligned(16)));
            *(uint4*)hb = *(const uint4*)((const u16*)Ain + aoff);
#pragma unroll
            for (int i = 0; i < 8; ++i) av[i] = b2f(hb[i]);
        }
        __half ah[8] __attribute__((aligned(16)));
        *(uint4*)ah = *(const uint4*)(agg + aoff);
        u16 ob[8] __attribute__((aligned(16)));
#pragma unroll
        for (int i = 0; i < 8; ++i) {
            float v = av[i];
            if (RELUIN) v = fmaxf(v, 0.f);
            ob[i] = f2b(v + __half2float(ah[i]));
        }
        pA = *(const uint4*)ob;
    };
    auto prefB = [&](const u16* W, int k0, int stride) {
        const uint4* wp = (const uint4*)(W + (size_t)brow * stride + k0);
#pragma unroll
        for (int q = 0; q < 4; ++q) pB[q] = wp[q];
    };

    f32x4 acc[4][4];
#pragma unroll
    for (int r = 0; r < 4; ++r)
#pragma unroll
        for (int c = 0; c < 4; ++c) acc[r][c] = (f32x4){0.f, 0.f, 0.f, 0.f};

    // ---- phase 1: hidden = relu((relu?(A)+agg) @ Wa + ba) ----
    prefA(0); prefB(WaT, 0, K);
    for (int k0 = 0; k0 < K; k0 += 32) {
        __syncthreads();                       // prev iter's reads done
        *(uint4*)&As2[aidx] = pA;
#pragma unroll
        for (int q = 0; q < 4; ++q) *(uint4*)&Bs2[bbase + q * 128] = pB[q];
        __syncthreads();
        if (k0 + 32 < K) { prefA(k0 + 32); prefB(WaT, k0 + 32, K); }
        bf16x8 a[4], b[4];
#pragma unroll
        for (int r = 0; r < 4; ++r) a[r] = *(const bf16x8*)&As2[(r * 64 + lane) * 8];
#pragma unroll
        for (int c = 0; c < 4; ++c) b[c] = *(const bf16x8*)&Bs2[((wave * 4 + c) * 64 + lane) * 8];
#pragma unroll
        for (int r = 0; r < 4; ++r)
#pragma unroll
            for (int c = 0; c < 4; ++c)
                acc[r][c] = __builtin_amdgcn_mfma_f32_16x16x32_bf16(a[r], b[c], acc[r][c], 0, 0, 0);
    }

    // epilogue 1 -> Hs2 (blocked A-layout for phase 2)
    // C/D layout: col = lane&15 (=lc), row = (lane>>4)*4 + i (=lr+i)
#pragma unroll
    for (int c = 0; c < 4; ++c) {
        const int n = cw0 + c * 16 + lc;
        const float bv = ba[n];
        const int nb = ((n >> 5) * 4) * 64 + ((n >> 3) & 3) * 16;
#pragma unroll
        for (int r = 0; r < 4; ++r)
#pragma unroll
            for (int i = 0; i < 4; ++i) {
                const int m = lr + i;          // row within 16 (m&15)
                Hs2[(nb + r * 64 + m) * 8 + (n & 7)] = f2b(fmaxf(acc[r][c][i] + bv, 0.f));
            }
    }

    // ---- phase 2: out = hidden @ Wb + bb ----
    f32x4 acc2[4][4];
#pragma unroll
    for (int r = 0; r < 4; ++r)
#pragma unroll
        for (int c = 0; c < 4; ++c) acc2[r][c] = (f32x4){0.f, 0.f, 0.f, 0.f};
    prefB(WbT, 0, 256);
    for (int k0 = 0; k0 < 256; k0 += 32) {
        __syncthreads();                       // Hs2 writes + prev Bs2 reads done
#pragma unroll
        for (int q = 0; q < 4; ++q) *(uint4*)&Bs2[bbase + q * 128] = pB[q];
        __syncthreads();
        if (k0 + 32 < 256) prefB(WbT, k0 + 32, 256);
        bf16x8 a[4], b[4];
#pragma unroll
        for (int r = 0; r < 4; ++r)
            a[r] = *(const bf16x8*)&Hs2[((k0 >> 5) * 256 + r * 64 + lane) * 8];
#pragma unroll
        for (int c = 0; c < 4; ++c) b[c] = *(const bf16x8*)&Bs2[((wave * 4 + c) * 64 + lane) * 8];
#pragma unroll
        for (int r = 0; r < 4; ++r)
#pragma unroll
            for (int c = 0; c < 4; ++c)
                acc2[r][c] = __builtin_amdgcn_mfma_f32_16x16x32_bf16(a[r], b[c], acc2[r][c], 0, 0, 0);
    }
#pragma unroll
    for (int c = 0; c < 4; ++c) {
        const int n = cw0 + c * 16 + lc;
        const float bv = bb[n];
#pragma unroll
        for (int r = 0; r < 4; ++r)
#pragma unroll
            for (int i = 0; i < 4; ++i)
                Hout[(size_t)(bm0 + r * 16 + lr + i) * 256 + n] = f2b(acc2[r][c][i] + bv);
    }
}

// ---------------------------------------------------------------------------
// Classifier linear: C[f32] = leaky(A[bf16] @ WT^T), N=512 via 2 n-blocks.
// ---------------------------------------------------------------------------
__global__ __launch_bounds__(256)
void k_lin(const u16* __restrict__ A, const u16* __restrict__ WT,
           float* __restrict__ C)
{
    __shared__ u16 As[64 * 40];
    __shared__ u16 Bs[256 * 40];
    const int tid = threadIdx.x, lane = tid & 63, wave = tid >> 6;
    const int bm0 = blockIdx.x * 64, bn0 = blockIdx.y * 256;
    const int fm = lane & 15, fk = (lane >> 4) * 8;
    const int lc = lane & 15, lr = (lane >> 4) * 4;
    const int cw0 = wave * 64;
    const int sr = tid >> 2, sc = tid & 3;

    f32x4 acc[4][4];
#pragma unroll
    for (int r = 0; r < 4; ++r)
#pragma unroll
        for (int c = 0; c < 4; ++c) acc[r][c] = (f32x4){0.f, 0.f, 0.f, 0.f};

    for (int k0 = 0; k0 < 256; k0 += 32) {
        *(uint4*)&As[sr * 40 + sc * 8] =
            *(const uint4*)(A + (size_t)(bm0 + sr) * 256 + k0 + sc * 8);
        {
            const uint4* wp = (const uint4*)(WT + (size_t)(bn0 + tid) * 256 + k0);
#pragma unroll
            for (int c = 0; c < 4; ++c)
                *(uint4*)&Bs[tid * 40 + c * 8] = wp[c];
        }
        __syncthreads();
        bf16x8 a[4], b[4];
#pragma unroll
        for (int r = 0; r < 4; ++r) a[r] = *(const bf16x8*)&As[(r * 16 + fm) * 40 + fk];
#pragma unroll
        for (int c = 0; c < 4; ++c) b[c] = *(const bf16x8*)&Bs[(cw0 + c * 16 + fm) * 40 + fk];
#pragma unroll
        for (int r = 0; r < 4; ++r)
#pragma unroll
            for (int c = 0; c < 4; ++c)
                acc[r][c] = __builtin_amdgcn_mfma_f32_16x16x32_bf16(a[r], b[c], acc[r][c], 0, 0, 0);
        __syncthreads();
    }
#pragma unroll
    for (int c = 0; c < 4; ++c) {
        const int col = bn0 + cw0 + c * 16 + lc;
#pragma unroll
        for (int r = 0; r < 4; ++r)
#pragma unroll
            for (int i = 0; i < 4; ++i) {
                float v = acc[r][c][i];
                v = (v >= 0.f) ? v : 0.01f * v;   // leaky
                C[(size_t)(bm0 + r * 16 + lr + i) * 512 + col] = v;
            }
    }
}

// ---------------------------------------------------------------------------
// Head kernels (f32)
// ---------------------------------------------------------------------------
__global__ void k_pool(const u16* __restrict__ H, u16* __restrict__ Xc)
{
    int c = blockIdx.x, f = threadIdx.x;          // 8192 blocks x 256
    const u16* p = H + (size_t)c * 25 * 256 + f;
    float s = 0.f;
#pragma unroll
    for (int j = 0; j < 25; ++j) s += b2f(p[j * 256]);
    Xc[(size_t)c * 256 + f] = f2b(s / 25.0f);
}

__global__ void k_setpool(const float* __restrict__ T, float* __restrict__ Tp)
{
    int tid = blockIdx.x * 256 + threadIdx.x;     // 4096*64
    int b = tid >> 6, s = tid & 63;
    float acc = 0.f;
#pragma unroll
    for (int c = 0; c < 2; ++c) {
        const float* row = T + ((size_t)(b * 2 + c)) * 512 + s;
        float mx = row[0];
#pragma unroll
        for (int m = 1; m < 8; ++m) mx = fmaxf(mx, row[m * 64]);
        acc += mx;
    }
    Tp[tid] = acc;
}

__global__ void k_fc1(const float* __restrict__ Tp, const float* __restrict__ w,
                      const float* __restrict__ b, float* __restrict__ T1)
{
    int tid = blockIdx.x * 256 + threadIdx.x;     // 4096*32
    int bb = tid >> 5, j = tid & 31;
    float s = b[j];
#pragma unroll
    for (int k = 0; k < 64; ++k) s += Tp[bb * 64 + k] * w[k * 32 + j];
    T1[tid] = s;
}

__global__ void k_bnstats(const float* __restrict__ T1, float* __restrict__ stats)
{
    __shared__ float r1[256], r2[256];
    const int j = blockIdx.x, t = threadIdx.x;    // 32 blocks
    float s = 0.f, ss = 0.f;
    for (int b = t; b < 4096; b += 256) {
        float v = T1[b * 32 + j];
        s += v; ss += v * v;
    }
    r1[t] = s; r2[t] = ss;
    __syncthreads();
    for (int off = 128; off > 0; off >>= 1) {
        if (t < off) { r1[t] += r1[t + off]; r2[t] += r2[t + off]; }
        __syncthreads();
    }
    if (t == 0) {
        float mu  = r1[0] * (1.f / 4096.f);
        float var = r2[0] * (1.f / 4096.f) - mu * mu;
        stats[j]      = mu;
        stats[32 + j] = 1.f / sqrtf(var + 1e-5f);
    }
}

__global__ void k_head(const float* __restrict__ T1, const float* __restrict__ stats,
                       const float* __restrict__ g, const float* __restrict__ bb,
                       const float* __restrict__ w2, const float* __restrict__ b2,
                       float* __restrict__ out)
{
    const int b = blockIdx.x * 256 + threadIdx.x; // 4096
    float l0 = b2[0], l1 = b2[1];
#pragma unroll
    for (int j = 0; j < 32; ++j) {
        float v = (T1[b * 32 + j] - stats[j]) * stats[32 + j] * g[j] + bb[j];
        v = (v >= 0.f) ? v : 0.01f * v;
        l0 += v * w2[j * 2];
        l1 += v * w2[j * 2 + 1];
    }
    float mx  = fmaxf(l0, l1);
    float lse = mx + logf(expf(l0 - mx) + expf(l1 - mx));
    out[b * 2]     = l0 - lse;
    out[b * 2 + 1] = l1 - lse;
}

// ---------------------------------------------------------------------------
extern "C" void kernel_launch(void* const* d_in, const int* in_sizes, int n_in,
                              void* d_out, int out_size, void* d_ws, size_t ws_size,
                              hipStream_t stream)
{
    (void)n_in; (void)out_size; (void)ws_size;
    constexpr int NN = 204800, NCOMP = 8192, NGRAPH = 4096;

    const float* x    = (const float*)d_in[0];
    const float* w0a  = (const float*)d_in[1];
    const float* b0a  = (const float*)d_in[2];
    const float* w0b  = (const float*)d_in[3];
    const float* b0b  = (const float*)d_in[4];
    const float* wra  = (const float*)d_in[5];
    const float* bra  = (const float*)d_in[6];
    const float* wrb  = (const float*)d_in[7];
    const float* brb  = (const float*)d_in[8];
    const float* Wc   = (const float*)d_in[9];
    const float* f1w  = (const float*)d_in[10];
    const float* f1b  = (const float*)d_in[11];
    const float* bng  = (const float*)d_in[12];
    const float* bnb  = (const float*)d_in[13];
    const float* f2w  = (const float*)d_in[14];
    const float* f2bb = (const float*)d_in[15];
    const int* ei   = (const int*)d_in[16];
    const int  E    = in_sizes[16] / 2;           // 409600
    const int* src  = ei;
    const int* dst  = ei + E;

    // ---- workspace layout (~205 MiB) ----
    char* ws = (char*)d_ws;
    __half* AGG = (__half*)ws;                               // [N,256] f16, 100 MiB
    u16*    H   = (u16*)(ws + (size_t)104857600);            // [N,256] bf16, 100 MiB
    u16*    wt  = (u16*)(ws + (size_t)209715200);            // transposed bf16 weights, 1 MiB
    u16 *WT0 = wt, *WT1 = wt + 65536, *WT2 = wt + 131072, *WT3 = wt + 196608,
        *WT4 = wt + 262144, *WT5 = wt + 327680, *WT6 = wt + 393216;
    // CSR arrays after weights:
    char* csr = ws + (size_t)210763776;
    int* cnt    = (int*)csr;                                 // [N]
    int* rowptr = (int*)(csr + 819200);                      // [N]
    int* cursor = (int*)(csr + 1638400);                     // [N]
    int* col    = (int*)(csr + 2457600);                     // [E]
    int* bsum   = (int*)(csr + 4096000);                     // [1024]
    int* bscan  = (int*)(csr + 4100096);                     // [1024]
    // head scratch reuses dead AGG region:
    u16*   Xc    = (u16*)ws;                                 // [8192,256] bf16
    float* Tfull = (float*)(ws + (size_t)16777216);          // [8192,512] f32
    float* Tp    = (float*)(ws + (size_t)33554432);          // [4096,64]
    float* T1    = (float*)(ws + (size_t)41943040);          // [4096,32]
    float* stats = (float*)(ws + (size_t)46137344);          // mu[32], rstd[32]

    const dim3 blk(256);
    const int NB = NN / 256;                                  // 800 scan blocks

    // ---- CSR build (once, reused by all 3 layers) ----
    hipMemsetAsync(cnt, 0, NN * 4, stream);
    k_count<<<(E + 255) / 256, blk, 0, stream>>>(dst, cnt, E);
    k_scan1<<<NB, blk, 0, stream>>>(cnt, rowptr, bsum, NN);
    k_scan2<<<1, blk, 0, stream>>>(bsum, bscan, NB);
    k_scan3<<<NB, blk, 0, stream>>>(rowptr, bscan, cursor, NN);
    k_fill<<<(E + 255) / 256, blk, 0, stream>>>(src, dst, cursor, col, E);

    // ---- pre-transpose weights (f32 -> bf16) ----
    k_T<<<128, blk, 0, stream>>>(w0a, WT0, 128, 256);
    k_T<<<256, blk, 0, stream>>>(w0b, WT1, 256, 256);
    k_T<<<256, blk, 0, stream>>>(wra,          WT2, 256, 256);
    k_T<<<256, blk, 0, stream>>>(wra + 65536,  WT3, 256, 256);
    k_T<<<256, blk, 0, stream>>>(wrb,          WT4, 256, 256);
    k_T<<<256, blk, 0, stream>>>(wrb + 65536,  WT5, 256, 256);
    k_T<<<512, blk, 0, stream>>>(Wc, WT6, 256, 512);

    // ---- layer 0 (K=128, A = x f32, no relu) ----
    k_gather<128, false, true><<<(NN * 16) / 256, blk, 0, stream>>>(x, cnt, rowptr, col, AGG, NN);
    k_gin<128, false, true><<<NN / 64, blk, 0, stream>>>(x, AGG, WT0, b0a, WT1, b0b, H);

    // ---- layers 1..2 (K=256, A = H bf16, relu on layer input) ----
    const u16* WA[2] = {WT2, WT3};
    const u16* WB[2] = {WT4, WT5};
    for (int l = 0; l < 2; ++l) {
        k_gather<256, true, false><<<(NN * 32) / 256, blk, 0, stream>>>(H, cnt, rowptr, col, AGG, NN);
        k_gin<256, true, false><<<NN / 64, blk, 0, stream>>>(
            H, AGG, WA[l], bra + (size_t)l * 256, WB[l], brb + (size_t)l * 256, H);
    }

    // ---- head ----
    k_pool<<<NCOMP, blk, 0, stream>>>(H, Xc);
    k_lin<<<dim3(NCOMP / 64, 2), blk, 0, stream>>>(Xc, WT6, Tfull);
    k_setpool<<<(NGRAPH * 64) / 256, blk, 0, stream>>>(Tfull, Tp);
    k_fc1<<<(NGRAPH * 32) / 256, blk, 0, stream>>>(Tp, f1w, f1b, T1);
    k_bnstats<<<32, blk, 0, stream>>>(T1, stats);
    k_head<<<NGRAPH / 256, blk, 0, stream>>>(T1, stats, bng, bnb, f2w, f2bb, (float*)d_out);
}

// Round 7
// 898.375 us; speedup vs baseline: 1.5125x; 1.5125x over previous
//
#include <hip/hip_runtime.h>
#include <hip/hip_fp16.h>
#include <math.h>

typedef unsigned short u16;
typedef float f32x4 __attribute__((ext_vector_type(4)));
typedef __bf16 bf16x8 __attribute__((ext_vector_type(8)));

__device__ __forceinline__ float b2f(u16 u) {
    union { unsigned int i; float f; } v; v.i = ((unsigned int)u) << 16; return v.f;
}
__device__ __forceinline__ u16 f2b(float f) {
    union { float f; unsigned int i; } v; v.f = f;
    unsigned int lsb = (v.i >> 16) & 1u;
    return (u16)((v.i + 0x7fffu + lsb) >> 16);   // RNE
}

// ---------------------------------------------------------------------------
// CSR build: counts -> block scan -> global scan -> fill
// ---------------------------------------------------------------------------
__global__ __launch_bounds__(256)
void k_count(const int* __restrict__ dst, int* __restrict__ cnt, int E)
{
    int e = blockIdx.x * 256 + threadIdx.x;
    if (e < E) atomicAdd(&cnt[dst[e]], 1);
}

__global__ __launch_bounds__(256)
void k_scan1(const int* __restrict__ cnt, int* __restrict__ rowptr,
             int* __restrict__ bsum, int N)
{
    __shared__ int s[256];
    int t = threadIdx.x, i = blockIdx.x * 256 + t;
    int v = (i < N) ? cnt[i] : 0;
    s[t] = v;
    __syncthreads();
#pragma unroll
    for (int off = 1; off < 256; off <<= 1) {
        int add = (t >= off) ? s[t - off] : 0;
        __syncthreads();
        s[t] += add;
        __syncthreads();
    }
    if (i < N) rowptr[i] = s[t] - v;
    if (t == 255) bsum[blockIdx.x] = s[255];
}

__global__ __launch_bounds__(256)
void k_scan2(const int* __restrict__ bsum, int* __restrict__ bscan, int nb)
{
    __shared__ int s[256];
    int t = threadIdx.x;
    int g[4], e[4];
    int base = t * 4;
#pragma unroll
    for (int j = 0; j < 4; ++j) g[j] = (base + j < nb) ? bsum[base + j] : 0;
    e[0] = 0; e[1] = g[0]; e[2] = g[0] + g[1]; e[3] = g[0] + g[1] + g[2];
    int tsum = e[3] + g[3];
    s[t] = tsum;
    __syncthreads();
#pragma unroll
    for (int off = 1; off < 256; off <<= 1) {
        int add = (t >= off) ? s[t - off] : 0;
        __syncthreads();
        s[t] += add;
        __syncthreads();
    }
    int texcl = s[t] - tsum;
#pragma unroll
    for (int j = 0; j < 4; ++j)
        if (base + j < nb) bscan[base + j] = texcl + e[j];
}

__global__ __launch_bounds__(256)
void k_scan3(int* __restrict__ rowptr, const int* __restrict__ bscan,
             int* __restrict__ cursor, int N)
{
    int i = blockIdx.x * 256 + threadIdx.x;
    if (i >= N) return;
    int r = rowptr[i] + bscan[i >> 8];
    rowptr[i] = r;
    cursor[i] = r;
}

__global__ __launch_bounds__(256)
void k_fill(const int* __restrict__ src, const int* __restrict__ dst,
            int* __restrict__ cursor, int* __restrict__ col, int E)
{
    int e = blockIdx.x * 256 + threadIdx.x;
    if (e >= E) return;
    int pos = atomicAdd(&cursor[dst[e]], 1);
    col[pos] = src[e];
}

// ---------------------------------------------------------------------------
// Gather aggregation: agg[i] = sum_{j in in(i)} relu?(h[col[j]]); f16 out.
// ---------------------------------------------------------------------------
template<int F, bool RELU, bool F32SRC>
__global__ __launch_bounds__(256)
void k_gather(const void* __restrict__ hsrc, const int* __restrict__ cnt,
              const int* __restrict__ rowptr, const int* __restrict__ col,
              __half* __restrict__ agg, int N)
{
    constexpr int CPE = F / 8;
    int tid = blockIdx.x * 256 + threadIdx.x;
    int node = tid / CPE, c = tid % CPE;
    if (node >= N) return;
    int n = cnt[node], rp = rowptr[node];
    float acc[8] = {0.f, 0.f, 0.f, 0.f, 0.f, 0.f, 0.f, 0.f};
    for (int j = 0; j < n; ++j) {
        int s = col[rp + j];
        if (F32SRC) {
            const float* p = (const float*)hsrc + (size_t)s * F + c * 8;
            float4 a = *(const float4*)p, b = *(const float4*)(p + 4);
            float xv[8] = {a.x, a.y, a.z, a.w, b.x, b.y, b.z, b.w};
#pragma unroll
            for (int i = 0; i < 8; ++i) acc[i] += RELU ? fmaxf(xv[i], 0.f) : xv[i];
        } else {
            u16 vs[8] __attribute__((aligned(16)));
            *(uint4*)vs = *(const uint4*)((const u16*)hsrc + (size_t)s * F + c * 8);
#pragma unroll
            for (int i = 0; i < 8; ++i) {
                float x = b2f(vs[i]);
                acc[i] += RELU ? fmaxf(x, 0.f) : x;
            }
        }
    }
    __half ob[8] __attribute__((aligned(16)));
#pragma unroll
    for (int i = 0; i < 8; ++i) ob[i] = __float2half(acc[i]);
    *(uint4*)(agg + (size_t)node * F + c * 8) = *(const uint4*)ob;
}

// transpose + f32->bf16 convert: out[n*K+k] = bf16(in[k*N+n])   (weights, tiny)
__global__ void k_T(const float* __restrict__ in, u16* __restrict__ out, int K, int N)
{
    int t = blockIdx.x * 256 + threadIdx.x;
    if (t >= K * N) return;
    int n = t / K, k = t % K;
    out[t] = f2b(in[k * N + n]);
}

// ---------------------------------------------------------------------------
// Fused GIN MLP v4: Hout(own 64 rows) = relu((relu?(A)+agg)@Wa+ba)@Wb+bb
// Block 64 rows x 256 cols, 4 waves in n; wave = 64x64, 4x4 frags of 16x16x32.
// LDS in MFMA-frag-blocked layout: every frag read is base + lane*16 B
// (conflict-free). As 4KB + Bs 16KB + Hs 32KB = 52KB -> 3 blocks/CU.
// NO register prefetch (R6's spilled 470MB to scratch), no min-waves bound.
// ---------------------------------------------------------------------------
template<int K, bool RELUIN, bool AF32>
__global__ __launch_bounds__(256)
void k_gin(const void* Ain, const __half* __restrict__ agg,
           const u16* __restrict__ WaT, const float* __restrict__ ba,
           const u16* __restrict__ WbT, const float* __restrict__ bb,
           u16* Hout)
{
    __shared__ u16 As2[64 * 32];     //  4 KB : idx=((m>>4)*64 + (k>>3)*16 + (m&15))*8 + (k&7)
    __shared__ u16 Bs2[256 * 32];    // 16 KB : idx=(((n>>6)*4+((n>>4)&3))*64 + (k>>3)*16 + (n&15))*8 + (k&7)
    __shared__ u16 Hs2[64 * 256];    // 32 KB : idx=((k>>5)*256 + (m>>4)*64 + ((k>>3)&3)*16 + (m&15))*8 + (k&7)

    const int tid = threadIdx.x, lane = tid & 63, wave = tid >> 6;
    const int bm0 = blockIdx.x * 64;
    const int lc = lane & 15, lr = (lane >> 4) * 4;
    const int cw0 = wave * 64;
    const int sr = tid >> 2, sc = tid & 3;                // A staging: row, k-chunk
    const int aidx = ((sr >> 4) * 64 + sc * 16 + (sr & 15)) * 8;
    const int bbase = (((tid >> 6) * 4 + ((tid >> 4) & 3)) * 64 + (tid & 15)) * 8;

    f32x4 acc[4][4];
#pragma unroll
    for (int r = 0; r < 4; ++r)
#pragma unroll
        for (int c = 0; c < 4; ++c) acc[r][c] = (f32x4){0.f, 0.f, 0.f, 0.f};

    // ---- phase 1: hidden = relu((relu?(A)+agg) @ Wa + ba) ----
    for (int k0 = 0; k0 < K; k0 += 32) {
        // A_eff staging (8 elems/thread, fused relu+agg)
        const size_t aoff = (size_t)(bm0 + sr) * K + k0 + sc * 8;
        float av[8];
        if (AF32) {
            const float* p = (const float*)Ain + aoff;
            float4 a = *(const float4*)p, b = *(const float4*)(p + 4);
            av[0]=a.x; av[1]=a.y; av[2]=a.z; av[3]=a.w;
            av[4]=b.x; av[5]=b.y; av[6]=b.z; av[7]=b.w;
        } else {
            u16 hb[8] __attribute__((aligned(16)));
            *(uint4*)hb = *(const uint4*)((const u16*)Ain + aoff);
#pragma unroll
            for (int i = 0; i < 8; ++i) av[i] = b2f(hb[i]);
        }
        __half ah[8] __attribute__((aligned(16)));
        *(uint4*)ah = *(const uint4*)(agg + aoff);
        u16 ob[8] __attribute__((aligned(16)));
#pragma unroll
        for (int i = 0; i < 8; ++i) {
            float v = av[i];
            if (RELUIN) v = fmaxf(v, 0.f);
            ob[i] = f2b(v + __half2float(ah[i]));
        }
        *(uint4*)&As2[aidx] = *(const uint4*)ob;
        // B staging: thread tid stages W row tid, 32 k (4x16B)
        {
            const uint4* wp = (const uint4*)(WaT + (size_t)tid * K + k0);
#pragma unroll
            for (int q = 0; q < 4; ++q) *(uint4*)&Bs2[bbase + q * 128] = wp[q];
        }
        __syncthreads();
        bf16x8 a[4], b[4];
#pragma unroll
        for (int r = 0; r < 4; ++r) a[r] = *(const bf16x8*)&As2[(r * 64 + lane) * 8];
#pragma unroll
        for (int c = 0; c < 4; ++c) b[c] = *(const bf16x8*)&Bs2[((wave * 4 + c) * 64 + lane) * 8];
#pragma unroll
        for (int r = 0; r < 4; ++r)
#pragma unroll
            for (int c = 0; c < 4; ++c)
                acc[r][c] = __builtin_amdgcn_mfma_f32_16x16x32_bf16(a[r], b[c], acc[r][c], 0, 0, 0);
        __syncthreads();
    }

    // epilogue 1 -> Hs2 (blocked A-layout for phase 2)
    // C/D layout: col = lane&15 (=lc), row = (lane>>4)*4 + i (=lr+i)
#pragma unroll
    for (int c = 0; c < 4; ++c) {
        const int n = cw0 + c * 16 + lc;           // hidden col = phase-2 k
        const float bv = ba[n];
        const int nb = (n >> 5) * 256 + ((n >> 3) & 3) * 16;
#pragma unroll
        for (int r = 0; r < 4; ++r)
#pragma unroll
            for (int i = 0; i < 4; ++i)
                Hs2[(nb + r * 64 + lr + i) * 8 + (n & 7)] = f2b(fmaxf(acc[r][c][i] + bv, 0.f));
    }
    __syncthreads();

    // ---- phase 2: out = hidden @ Wb + bb ----
    f32x4 acc2[4][4];
#pragma unroll
    for (int r = 0; r < 4; ++r)
#pragma unroll
        for (int c = 0; c < 4; ++c) acc2[r][c] = (f32x4){0.f, 0.f, 0.f, 0.f};
    for (int k0 = 0; k0 < 256; k0 += 32) {
        {
            const uint4* wp = (const uint4*)(WbT + (size_t)tid * 256 + k0);
#pragma unroll
            for (int q = 0; q < 4; ++q) *(uint4*)&Bs2[bbase + q * 128] = wp[q];
        }
        __syncthreads();
        bf16x8 a[4], b[4];
#pragma unroll
        for (int r = 0; r < 4; ++r)
            a[r] = *(const bf16x8*)&Hs2[((k0 >> 5) * 256 + r * 64 + lane) * 8];
#pragma unroll
        for (int c = 0; c < 4; ++c) b[c] = *(const bf16x8*)&Bs2[((wave * 4 + c) * 64 + lane) * 8];
#pragma unroll
        for (int r = 0; r < 4; ++r)
#pragma unroll
            for (int c = 0; c < 4; ++c)
                acc2[r][c] = __builtin_amdgcn_mfma_f32_16x16x32_bf16(a[r], b[c], acc2[r][c], 0, 0, 0);
        __syncthreads();
    }
#pragma unroll
    for (int c = 0; c < 4; ++c) {
        const int n = cw0 + c * 16 + lc;
        const float bv = bb[n];
#pragma unroll
        for (int r = 0; r < 4; ++r)
#pragma unroll
            for (int i = 0; i < 4; ++i)
                Hout[(size_t)(bm0 + r * 16 + lr + i) * 256 + n] = f2b(acc2[r][c][i] + bv);
    }
}

// ---------------------------------------------------------------------------
// Classifier linear: C[f32] = leaky(A[bf16] @ WT^T), N=512 via 2 n-blocks.
// ---------------------------------------------------------------------------
__global__ __launch_bounds__(256)
void k_lin(const u16* __restrict__ A, const u16* __restrict__ WT,
           float* __restrict__ C)
{
    __shared__ u16 As[64 * 40];
    __shared__ u16 Bs[256 * 40];
    const int tid = threadIdx.x, lane = tid & 63, wave = tid >> 6;
    const int bm0 = blockIdx.x * 64, bn0 = blockIdx.y * 256;
    const int fm = lane & 15, fk = (lane >> 4) * 8;
    const int lc = lane & 15, lr = (lane >> 4) * 4;
    const int cw0 = wave * 64;
    const int sr = tid >> 2, sc = tid & 3;

    f32x4 acc[4][4];
#pragma unroll
    for (int r = 0; r < 4; ++r)
#pragma unroll
        for (int c = 0; c < 4; ++c) acc[r][c] = (f32x4){0.f, 0.f, 0.f, 0.f};

    for (int k0 = 0; k0 < 256; k0 += 32) {
        *(uint4*)&As[sr * 40 + sc * 8] =
            *(const uint4*)(A + (size_t)(bm0 + sr) * 256 + k0 + sc * 8);
        {
            const uint4* wp = (const uint4*)(WT + (size_t)(bn0 + tid) * 256 + k0);
#pragma unroll
            for (int c = 0; c < 4; ++c)
                *(uint4*)&Bs[tid * 40 + c * 8] = wp[c];
        }
        __syncthreads();
        bf16x8 a[4], b[4];
#pragma unroll
        for (int r = 0; r < 4; ++r) a[r] = *(const bf16x8*)&As[(r * 16 + fm) * 40 + fk];
#pragma unroll
        for (int c = 0; c < 4; ++c) b[c] = *(const bf16x8*)&Bs[(cw0 + c * 16 + fm) * 40 + fk];
#pragma unroll
        for (int r = 0; r < 4; ++r)
#pragma unroll
            for (int c = 0; c < 4; ++c)
                acc[r][c] = __builtin_amdgcn_mfma_f32_16x16x32_bf16(a[r], b[c], acc[r][c], 0, 0, 0);
        __syncthreads();
    }
#pragma unroll
    for (int c = 0; c < 4; ++c) {
        const int col = bn0 + cw0 + c * 16 + lc;
#pragma unroll
        for (int r = 0; r < 4; ++r)
#pragma unroll
            for (int i = 0; i < 4; ++i) {
                float v = acc[r][c][i];
                v = (v >= 0.f) ? v : 0.01f * v;   // leaky
                C[(size_t)(bm0 + r * 16 + lr + i) * 512 + col] = v;
            }
    }
}

// ---------------------------------------------------------------------------
// Head kernels (f32)
// ---------------------------------------------------------------------------
__global__ void k_pool(const u16* __restrict__ H, u16* __restrict__ Xc)
{
    int c = blockIdx.x, f = threadIdx.x;          // 8192 blocks x 256
    const u16* p = H + (size_t)c * 25 * 256 + f;
    float s = 0.f;
#pragma unroll
    for (int j = 0; j < 25; ++j) s += b2f(p[j * 256]);
    Xc[(size_t)c * 256 + f] = f2b(s / 25.0f);
}

__global__ void k_setpool(const float* __restrict__ T, float* __restrict__ Tp)
{
    int tid = blockIdx.x * 256 + threadIdx.x;     // 4096*64
    int b = tid >> 6, s = tid & 63;
    float acc = 0.f;
#pragma unroll
    for (int c = 0; c < 2; ++c) {
        const float* row = T + ((size_t)(b * 2 + c)) * 512 + s;
        float mx = row[0];
#pragma unroll
        for (int m = 1; m < 8; ++m) mx = fmaxf(mx, row[m * 64]);
        acc += mx;
    }
    Tp[tid] = acc;
}

__global__ void k_fc1(const float* __restrict__ Tp, const float* __restrict__ w,
                      const float* __restrict__ b, float* __restrict__ T1)
{
    int tid = blockIdx.x * 256 + threadIdx.x;     // 4096*32
    int bb = tid >> 5, j = tid & 31;
    float s = b[j];
#pragma unroll
    for (int k = 0; k < 64; ++k) s += Tp[bb * 64 + k] * w[k * 32 + j];
    T1[tid] = s;
}

__global__ void k_bnstats(const float* __restrict__ T1, float* __restrict__ stats)
{
    __shared__ float r1[256], r2[256];
    const int j = blockIdx.x, t = threadIdx.x;    // 32 blocks
    float s = 0.f, ss = 0.f;
    for (int b = t; b < 4096; b += 256) {
        float v = T1[b * 32 + j];
        s += v; ss += v * v;
    }
    r1[t] = s; r2[t] = ss;
    __syncthreads();
    for (int off = 128; off > 0; off >>= 1) {
        if (t < off) { r1[t] += r1[t + off]; r2[t] += r2[t + off]; }
        __syncthreads();
    }
    if (t == 0) {
        float mu  = r1[0] * (1.f / 4096.f);
        float var = r2[0] * (1.f / 4096.f) - mu * mu;
        stats[j]      = mu;
        stats[32 + j] = 1.f / sqrtf(var + 1e-5f);
    }
}

__global__ void k_head(const float* __restrict__ T1, const float* __restrict__ stats,
                       const float* __restrict__ g, const float* __restrict__ bb,
                       const float* __restrict__ w2, const float* __restrict__ b2,
                       float* __restrict__ out)
{
    const int b = blockIdx.x * 256 + threadIdx.x; // 4096
    float l0 = b2[0], l1 = b2[1];
#pragma unroll
    for (int j = 0; j < 32; ++j) {
        float v = (T1[b * 32 + j] - stats[j]) * stats[32 + j] * g[j] + bb[j];
        v = (v >= 0.f) ? v : 0.01f * v;
        l0 += v * w2[j * 2];
        l1 += v * w2[j * 2 + 1];
    }
    float mx  = fmaxf(l0, l1);
    float lse = mx + logf(expf(l0 - mx) + expf(l1 - mx));
    out[b * 2]     = l0 - lse;
    out[b * 2 + 1] = l1 - lse;
}

// ---------------------------------------------------------------------------
extern "C" void kernel_launch(void* const* d_in, const int* in_sizes, int n_in,
                              void* d_out, int out_size, void* d_ws, size_t ws_size,
                              hipStream_t stream)
{
    (void)n_in; (void)out_size; (void)ws_size;
    constexpr int NN = 204800, NCOMP = 8192, NGRAPH = 4096;

    const float* x    = (const float*)d_in[0];
    const float* w0a  = (const float*)d_in[1];
    const float* b0a  = (const float*)d_in[2];
    const float* w0b  = (const float*)d_in[3];
    const float* b0b  = (const float*)d_in[4];
    const float* wra  = (const float*)d_in[5];
    const float* bra  = (const float*)d_in[6];
    const float* wrb  = (const float*)d_in[7];
    const float* brb  = (const float*)d_in[8];
    const float* Wc   = (const float*)d_in[9];
    const float* f1w  = (const float*)d_in[10];
    const float* f1b  = (const float*)d_in[11];
    const float* bng  = (const float*)d_in[12];
    const float* bnb  = (const float*)d_in[13];
    const float* f2w  = (const float*)d_in[14];
    const float* f2bb = (const float*)d_in[15];
    const int* ei   = (const int*)d_in[16];
    const int  E    = in_sizes[16] / 2;           // 409600
    const int* src  = ei;
    const int* dst  = ei + E;

    // ---- workspace layout (~205 MiB) ----
    char* ws = (char*)d_ws;
    __half* AGG = (__half*)ws;                               // [N,256] f16, 100 MiB
    u16*    H   = (u16*)(ws + (size_t)104857600);            // [N,256] bf16, 100 MiB
    u16*    wt  = (u16*)(ws + (size_t)209715200);            // transposed bf16 weights, 1 MiB
    u16 *WT0 = wt, *WT1 = wt + 65536, *WT2 = wt + 131072, *WT3 = wt + 196608,
        *WT4 = wt + 262144, *WT5 = wt + 327680, *WT6 = wt + 393216;
    // CSR arrays after weights:
    char* csr = ws + (size_t)210763776;
    int* cnt    = (int*)csr;                                 // [N]
    int* rowptr = (int*)(csr + 819200);                      // [N]
    int* cursor = (int*)(csr + 1638400);                     // [N]
    int* col    = (int*)(csr + 2457600);                     // [E]
    int* bsum   = (int*)(csr + 4096000);                     // [1024]
    int* bscan  = (int*)(csr + 4100096);                     // [1024]
    // head scratch reuses dead AGG region:
    u16*   Xc    = (u16*)ws;                                 // [8192,256] bf16
    float* Tfull = (float*)(ws + (size_t)16777216);          // [8192,512] f32
    float* Tp    = (float*)(ws + (size_t)33554432);          // [4096,64]
    float* T1    = (float*)(ws + (size_t)41943040);          // [4096,32]
    float* stats = (float*)(ws + (size_t)46137344);          // mu[32], rstd[32]

    const dim3 blk(256);
    const int NB = NN / 256;                                  // 800 scan blocks

    // ---- CSR build (once, reused by all 3 layers) ----
    hipMemsetAsync(cnt, 0, NN * 4, stream);
    k_count<<<(E + 255) / 256, blk, 0, stream>>>(dst, cnt, E);
    k_scan1<<<NB, blk, 0, stream>>>(cnt, rowptr, bsum, NN);
    k_scan2<<<1, blk, 0, stream>>>(bsum, bscan, NB);
    k_scan3<<<NB, blk, 0, stream>>>(rowptr, bscan, cursor, NN);
    k_fill<<<(E + 255) / 256, blk, 0, stream>>>(src, dst, cursor, col, E);

    // ---- pre-transpose weights (f32 -> bf16) ----
    k_T<<<128, blk, 0, stream>>>(w0a, WT0, 128, 256);
    k_T<<<256, blk, 0, stream>>>(w0b, WT1, 256, 256);
    k_T<<<256, blk, 0, stream>>>(wra,          WT2, 256, 256);
    k_T<<<256, blk, 0, stream>>>(wra + 65536,  WT3, 256, 256);
    k_T<<<256, blk, 0, stream>>>(wrb,          WT4, 256, 256);
    k_T<<<256, blk, 0, stream>>>(wrb + 65536,  WT5, 256, 256);
    k_T<<<512, blk, 0, stream>>>(Wc, WT6, 256, 512);

    // ---- layer 0 (K=128, A = x f32, no relu) ----
    k_gather<128, false, true><<<(NN * 16) / 256, blk, 0, stream>>>(x, cnt, rowptr, col, AGG, NN);
    k_gin<128, false, true><<<NN / 64, blk, 0, stream>>>(x, AGG, WT0, b0a, WT1, b0b, H);

    // ---- layers 1..2 (K=256, A = H bf16, relu on layer input) ----
    const u16* WA[2] = {WT2, WT3};
    const u16* WB[2] = {WT4, WT5};
    for (int l = 0; l < 2; ++l) {
        k_gather<256, true, false><<<(NN * 32) / 256, blk, 0, stream>>>(H, cnt, rowptr, col, AGG, NN);
        k_gin<256, true, false><<<NN / 64, blk, 0, stream>>>(
            H, AGG, WA[l], bra + (size_t)l * 256, WB[l], brb + (size_t)l * 256, H);
    }

    // ---- head ----
    k_pool<<<NCOMP, blk, 0, stream>>>(H, Xc);
    k_lin<<<dim3(NCOMP / 64, 2), blk, 0, stream>>>(Xc, WT6, Tfull);
    k_setpool<<<(NGRAPH * 64) / 256, blk, 0, stream>>>(Tfull, Tp);
    k_fc1<<<(NGRAPH * 32) / 256, blk, 0, stream>>>(Tp, f1w, f1b, T1);
    k_bnstats<<<32, blk, 0, stream>>>(T1, stats);
    k_head<<<NGRAPH / 256, blk, 0, stream>>>(T1, stats, bng, bnb, f2w, f2bb, (float*)d_out);
}

// Round 8
// 801.802 us; speedup vs baseline: 1.6946x; 1.1204x over previous
//
#include <hip/hip_runtime.h>
#include <hip/hip_fp16.h>
#include <math.h>

typedef unsigned short u16;
typedef float f32x4 __attribute__((ext_vector_type(4)));
typedef __bf16 bf16x8 __attribute__((ext_vector_type(8)));

__device__ __forceinline__ float b2f(u16 u) {
    union { unsigned int i; float f; } v; v.i = ((unsigned int)u) << 16; return v.f;
}
__device__ __forceinline__ u16 f2b(float f) {
    union { float f; unsigned int i; } v; v.f = f;
    unsigned int lsb = (v.i >> 16) & 1u;
    return (u16)((v.i + 0x7fffu + lsb) >> 16);   // RNE
}

// async global->LDS, 16B per lane; lds dest = wave-uniform base + lane*16
__device__ __forceinline__ void gld16(const u16* g, u16* l) {
    __builtin_amdgcn_global_load_lds(
        (const __attribute__((address_space(1))) unsigned int*)g,
        (__attribute__((address_space(3))) unsigned int*)l,
        16, 0, 0);
}

// ---------------------------------------------------------------------------
// CSR build: counts -> block scan -> global scan -> fill
// ---------------------------------------------------------------------------
__global__ __launch_bounds__(256)
void k_count(const int* __restrict__ dst, int* __restrict__ cnt, int E)
{
    int e = blockIdx.x * 256 + threadIdx.x;
    if (e < E) atomicAdd(&cnt[dst[e]], 1);
}

__global__ __launch_bounds__(256)
void k_scan1(const int* __restrict__ cnt, int* __restrict__ rowptr,
             int* __restrict__ bsum, int N)
{
    __shared__ int s[256];
    int t = threadIdx.x, i = blockIdx.x * 256 + t;
    int v = (i < N) ? cnt[i] : 0;
    s[t] = v;
    __syncthreads();
#pragma unroll
    for (int off = 1; off < 256; off <<= 1) {
        int add = (t >= off) ? s[t - off] : 0;
        __syncthreads();
        s[t] += add;
        __syncthreads();
    }
    if (i < N) rowptr[i] = s[t] - v;
    if (t == 255) bsum[blockIdx.x] = s[255];
}

__global__ __launch_bounds__(256)
void k_scan2(const int* __restrict__ bsum, int* __restrict__ bscan, int nb)
{
    __shared__ int s[256];
    int t = threadIdx.x;
    int g[4], e[4];
    int base = t * 4;
#pragma unroll
    for (int j = 0; j < 4; ++j) g[j] = (base + j < nb) ? bsum[base + j] : 0;
    e[0] = 0; e[1] = g[0]; e[2] = g[0] + g[1]; e[3] = g[0] + g[1] + g[2];
    int tsum = e[3] + g[3];
    s[t] = tsum;
    __syncthreads();
#pragma unroll
    for (int off = 1; off < 256; off <<= 1) {
        int add = (t >= off) ? s[t - off] : 0;
        __syncthreads();
        s[t] += add;
        __syncthreads();
    }
    int texcl = s[t] - tsum;
#pragma unroll
    for (int j = 0; j < 4; ++j)
        if (base + j < nb) bscan[base + j] = texcl + e[j];
}

__global__ __launch_bounds__(256)
void k_scan3(int* __restrict__ rowptr, const int* __restrict__ bscan,
             int* __restrict__ cursor, int N)
{
    int i = blockIdx.x * 256 + threadIdx.x;
    if (i >= N) return;
    int r = rowptr[i] + bscan[i >> 8];
    rowptr[i] = r;
    cursor[i] = r;
}

__global__ __launch_bounds__(256)
void k_fill(const int* __restrict__ src, const int* __restrict__ dst,
            int* __restrict__ cursor, int* __restrict__ col, int E)
{
    int e = blockIdx.x * 256 + threadIdx.x;
    if (e >= E) return;
    int pos = atomicAdd(&cursor[dst[e]], 1);
    col[pos] = src[e];
}

// ---------------------------------------------------------------------------
// Aggregation + GIN-sum fused: Aeff[i] = bf16(relu?(h[i]) + sum_j relu?(h[col[j]]))
// f32 accumulate, one bf16 round. CPE consecutive threads per node.
// ---------------------------------------------------------------------------
template<int F, bool RELU, bool F32SRC>
__global__ __launch_bounds__(256)
void k_aggr(const void* __restrict__ hsrc, const int* __restrict__ cnt,
            const int* __restrict__ rowptr, const int* __restrict__ col,
            u16* __restrict__ aeff, int N)
{
    constexpr int CPE = F / 8;
    int tid = blockIdx.x * 256 + threadIdx.x;
    int node = tid / CPE, c = tid % CPE;
    if (node >= N) return;
    int n = cnt[node], rp = rowptr[node];
    float acc[8];
    // own row
    if (F32SRC) {
        const float* p = (const float*)hsrc + (size_t)node * F + c * 8;
        float4 a = *(const float4*)p, b = *(const float4*)(p + 4);
        float xv[8] = {a.x, a.y, a.z, a.w, b.x, b.y, b.z, b.w};
#pragma unroll
        for (int i = 0; i < 8; ++i) acc[i] = RELU ? fmaxf(xv[i], 0.f) : xv[i];
    } else {
        u16 vs[8] __attribute__((aligned(16)));
        *(uint4*)vs = *(const uint4*)((const u16*)hsrc + (size_t)node * F + c * 8);
#pragma unroll
        for (int i = 0; i < 8; ++i) {
            float x = b2f(vs[i]);
            acc[i] = RELU ? fmaxf(x, 0.f) : x;
        }
    }
    // neighbors
    for (int j = 0; j < n; ++j) {
        int s = col[rp + j];
        if (F32SRC) {
            const float* p = (const float*)hsrc + (size_t)s * F + c * 8;
            float4 a = *(const float4*)p, b = *(const float4*)(p + 4);
            float xv[8] = {a.x, a.y, a.z, a.w, b.x, b.y, b.z, b.w};
#pragma unroll
            for (int i = 0; i < 8; ++i) acc[i] += RELU ? fmaxf(xv[i], 0.f) : xv[i];
        } else {
            u16 vs[8] __attribute__((aligned(16)));
            *(uint4*)vs = *(const uint4*)((const u16*)hsrc + (size_t)s * F + c * 8);
#pragma unroll
            for (int i = 0; i < 8; ++i) {
                float x = b2f(vs[i]);
                acc[i] += RELU ? fmaxf(x, 0.f) : x;
            }
        }
    }
    u16 ob[8] __attribute__((aligned(16)));
#pragma unroll
    for (int i = 0; i < 8; ++i) ob[i] = f2b(acc[i]);
    *(uint4*)(aeff + (size_t)node * F + c * 8) = *(const uint4*)ob;
}

// transpose + f32->bf16 convert: out[n*K+k] = bf16(in[k*N+n])   (weights, tiny)
__global__ void k_T(const float* __restrict__ in, u16* __restrict__ out, int K, int N)
{
    int t = blockIdx.x * 256 + threadIdx.x;
    if (t >= K * N) return;
    int n = t / K, k = t % K;
    out[t] = f2b(in[k * N + n]);
}

// ---------------------------------------------------------------------------
// Fused GIN MLP v5: Hout = relu(Aeff @ Wa + ba) @ Wb + bb, Aeff bf16 [N,K].
// Block 64 rows x 256 cols, 4 waves in n; wave = 64x64, 4x4 frags of 16x16x32.
// A/B staging via global_load_lds width=16 (pure DMA, no VGPR round trip).
// LDS blocked layout: lane l of wave w stages row w*16+(l&15), k-chunk l>>4
// at base + lane*16 -> frag reads are slot = base + lane*16 (conflict-free).
// As 4KB + Bs 16KB + Hs 32KB = 52KB.
// ---------------------------------------------------------------------------
template<int K>
__global__ __launch_bounds__(256)
void k_gin(const u16* __restrict__ Aeff,
           const u16* __restrict__ WaT, const float* __restrict__ ba,
           const u16* __restrict__ WbT, const float* __restrict__ bb,
           u16* __restrict__ Hout)
{
    __shared__ u16 As2[64 * 32];     //  4 KB
    __shared__ u16 Bs2[256 * 32];    // 16 KB
    __shared__ u16 Hs2[64 * 256];    // 32 KB

    const int tid = threadIdx.x, lane = tid & 63, wave = tid >> 6;
    const int bm0 = blockIdx.x * 64;
    const int lc = lane & 15, lr = (lane >> 4) * 4;
    const int cw0 = wave * 64;
    const int l15 = lane & 15, lq = lane >> 4;   // DMA lane roles

    u16* aDst = As2 + wave * 512;                 // wave-uniform LDS base
    const u16* aRow = Aeff + (size_t)(bm0 + wave * 16 + l15) * K + lq * 8;

    f32x4 acc[4][4];
#pragma unroll
    for (int r = 0; r < 4; ++r)
#pragma unroll
        for (int c = 0; c < 4; ++c) acc[r][c] = (f32x4){0.f, 0.f, 0.f, 0.f};

    // ---- phase 1: hidden = relu(Aeff @ Wa + ba) ----
    for (int k0 = 0; k0 < K; k0 += 32) {
        gld16(aRow + k0, aDst);
#pragma unroll
        for (int c = 0; c < 4; ++c)
            gld16(WaT + (size_t)(cw0 + c * 16 + l15) * K + k0 + lq * 8,
                  Bs2 + (wave * 4 + c) * 512);
        __syncthreads();                          // drain DMA (vmcnt) + barrier
        bf16x8 a[4], b[4];
#pragma unroll
        for (int r = 0; r < 4; ++r) a[r] = *(const bf16x8*)&As2[(r * 64 + lane) * 8];
#pragma unroll
        for (int c = 0; c < 4; ++c) b[c] = *(const bf16x8*)&Bs2[((wave * 4 + c) * 64 + lane) * 8];
#pragma unroll
        for (int r = 0; r < 4; ++r)
#pragma unroll
            for (int c = 0; c < 4; ++c)
                acc[r][c] = __builtin_amdgcn_mfma_f32_16x16x32_bf16(a[r], b[c], acc[r][c], 0, 0, 0);
        __syncthreads();                          // reads done -> next DMA safe
    }

    // epilogue 1 -> Hs2 (blocked A-layout for phase 2)
    // C/D layout: col = lane&15 (=lc), row = (lane>>4)*4 + i (=lr+i)
#pragma unroll
    for (int c = 0; c < 4; ++c) {
        const int n = cw0 + c * 16 + lc;           // hidden col = phase-2 k
        const float bv = ba[n];
        const int nb = (n >> 5) * 256 + ((n >> 3) & 3) * 16;
#pragma unroll
        for (int r = 0; r < 4; ++r)
#pragma unroll
            for (int i = 0; i < 4; ++i)
                Hs2[(nb + r * 64 + lr + i) * 8 + (n & 7)] = f2b(fmaxf(acc[r][c][i] + bv, 0.f));
    }
    __syncthreads();

    // ---- phase 2: out = hidden @ Wb + bb ----
    f32x4 acc2[4][4];
#pragma unroll
    for (int r = 0; r < 4; ++r)
#pragma unroll
        for (int c = 0; c < 4; ++c) acc2[r][c] = (f32x4){0.f, 0.f, 0.f, 0.f};
    for (int k0 = 0; k0 < 256; k0 += 32) {
#pragma unroll
        for (int c = 0; c < 4; ++c)
            gld16(WbT + (size_t)(cw0 + c * 16 + l15) * 256 + k0 + lq * 8,
                  Bs2 + (wave * 4 + c) * 512);
        __syncthreads();
        bf16x8 a[4], b[4];
#pragma unroll
        for (int r = 0; r < 4; ++r)
            a[r] = *(const bf16x8*)&Hs2[((k0 >> 5) * 256 + r * 64 + lane) * 8];
#pragma unroll
        for (int c = 0; c < 4; ++c) b[c] = *(const bf16x8*)&Bs2[((wave * 4 + c) * 64 + lane) * 8];
#pragma unroll
        for (int r = 0; r < 4; ++r)
#pragma unroll
            for (int c = 0; c < 4; ++c)
                acc2[r][c] = __builtin_amdgcn_mfma_f32_16x16x32_bf16(a[r], b[c], acc2[r][c], 0, 0, 0);
        __syncthreads();
    }
#pragma unroll
    for (int c = 0; c < 4; ++c) {
        const int n = cw0 + c * 16 + lc;
        const float bv = bb[n];
#pragma unroll
        for (int r = 0; r < 4; ++r)
#pragma unroll
            for (int i = 0; i < 4; ++i)
                Hout[(size_t)(bm0 + r * 16 + lr + i) * 256 + n] = f2b(acc2[r][c][i] + bv);
    }
}

// ---------------------------------------------------------------------------
// Classifier linear: C[f32] = leaky(A[bf16] @ WT^T), N=512 via 2 n-blocks.
// ---------------------------------------------------------------------------
__global__ __launch_bounds__(256)
void k_lin(const u16* __restrict__ A, const u16* __restrict__ WT,
           float* __restrict__ C)
{
    __shared__ u16 As[64 * 40];
    __shared__ u16 Bs[256 * 40];
    const int tid = threadIdx.x, lane = tid & 63, wave = tid >> 6;
    const int bm0 = blockIdx.x * 64, bn0 = blockIdx.y * 256;
    const int fm = lane & 15, fk = (lane >> 4) * 8;
    const int lc = lane & 15, lr = (lane >> 4) * 4;
    const int cw0 = wave * 64;
    const int sr = tid >> 2, sc = tid & 3;

    f32x4 acc[4][4];
#pragma unroll
    for (int r = 0; r < 4; ++r)
#pragma unroll
        for (int c = 0; c < 4; ++c) acc[r][c] = (f32x4){0.f, 0.f, 0.f, 0.f};

    for (int k0 = 0; k0 < 256; k0 += 32) {
        *(uint4*)&As[sr * 40 + sc * 8] =
            *(const uint4*)(A + (size_t)(bm0 + sr) * 256 + k0 + sc * 8);
        {
            const uint4* wp = (const uint4*)(WT + (size_t)(bn0 + tid) * 256 + k0);
#pragma unroll
            for (int c = 0; c < 4; ++c)
                *(uint4*)&Bs[tid * 40 + c * 8] = wp[c];
        }
        __syncthreads();
        bf16x8 a[4], b[4];
#pragma unroll
        for (int r = 0; r < 4; ++r) a[r] = *(const bf16x8*)&As[(r * 16 + fm) * 40 + fk];
#pragma unroll
        for (int c = 0; c < 4; ++c) b[c] = *(const bf16x8*)&Bs[(cw0 + c * 16 + fm) * 40 + fk];
#pragma unroll
        for (int r = 0; r < 4; ++r)
#pragma unroll
            for (int c = 0; c < 4; ++c)
                acc[r][c] = __builtin_amdgcn_mfma_f32_16x16x32_bf16(a[r], b[c], acc[r][c], 0, 0, 0);
        __syncthreads();
    }
#pragma unroll
    for (int c = 0; c < 4; ++c) {
        const int col = bn0 + cw0 + c * 16 + lc;
#pragma unroll
        for (int r = 0; r < 4; ++r)
#pragma unroll
            for (int i = 0; i < 4; ++i) {
                float v = acc[r][c][i];
                v = (v >= 0.f) ? v : 0.01f * v;   // leaky
                C[(size_t)(bm0 + r * 16 + lr + i) * 512 + col] = v;
            }
    }
}

// ---------------------------------------------------------------------------
// Head kernels (f32)
// ---------------------------------------------------------------------------
__global__ void k_pool(const u16* __restrict__ H, u16* __restrict__ Xc)
{
    int c = blockIdx.x, f = threadIdx.x;          // 8192 blocks x 256
    const u16* p = H + (size_t)c * 25 * 256 + f;
    float s = 0.f;
#pragma unroll
    for (int j = 0; j < 25; ++j) s += b2f(p[j * 256]);
    Xc[(size_t)c * 256 + f] = f2b(s / 25.0f);
}

__global__ void k_setpool(const float* __restrict__ T, float* __restrict__ Tp)
{
    int tid = blockIdx.x * 256 + threadIdx.x;     // 4096*64
    int b = tid >> 6, s = tid & 63;
    float acc = 0.f;
#pragma unroll
    for (int c = 0; c < 2; ++c) {
        const float* row = T + ((size_t)(b * 2 + c)) * 512 + s;
        float mx = row[0];
#pragma unroll
        for (int m = 1; m < 8; ++m) mx = fmaxf(mx, row[m * 64]);
        acc += mx;
    }
    Tp[tid] = acc;
}

__global__ void k_fc1(const float* __restrict__ Tp, const float* __restrict__ w,
                      const float* __restrict__ b, float* __restrict__ T1)
{
    int tid = blockIdx.x * 256 + threadIdx.x;     // 4096*32
    int bb = tid >> 5, j = tid & 31;
    float s = b[j];
#pragma unroll
    for (int k = 0; k < 64; ++k) s += Tp[bb * 64 + k] * w[k * 32 + j];
    T1[tid] = s;
}

__global__ void k_bnstats(const float* __restrict__ T1, float* __restrict__ stats)
{
    __shared__ float r1[256], r2[256];
    const int j = blockIdx.x, t = threadIdx.x;    // 32 blocks
    float s = 0.f, ss = 0.f;
    for (int b = t; b < 4096; b += 256) {
        float v = T1[b * 32 + j];
        s += v; ss += v * v;
    }
    r1[t] = s; r2[t] = ss;
    __syncthreads();
    for (int off = 128; off > 0; off >>= 1) {
        if (t < off) { r1[t] += r1[t + off]; r2[t] += r2[t + off]; }
        __syncthreads();
    }
    if (t == 0) {
        float mu  = r1[0] * (1.f / 4096.f);
        float var = r2[0] * (1.f / 4096.f) - mu * mu;
        stats[j]      = mu;
        stats[32 + j] = 1.f / sqrtf(var + 1e-5f);
    }
}

__global__ void k_head(const float* __restrict__ T1, const float* __restrict__ stats,
                       const float* __restrict__ g, const float* __restrict__ bb,
                       const float* __restrict__ w2, const float* __restrict__ b2,
                       float* __restrict__ out)
{
    const int b = blockIdx.x * 256 + threadIdx.x; // 4096
    float l0 = b2[0], l1 = b2[1];
#pragma unroll
    for (int j = 0; j < 32; ++j) {
        float v = (T1[b * 32 + j] - stats[j]) * stats[32 + j] * g[j] + bb[j];
        v = (v >= 0.f) ? v : 0.01f * v;
        l0 += v * w2[j * 2];
        l1 += v * w2[j * 2 + 1];
    }
    float mx  = fmaxf(l0, l1);
    float lse = mx + logf(expf(l0 - mx) + expf(l1 - mx));
    out[b * 2]     = l0 - lse;
    out[b * 2 + 1] = l1 - lse;
}

// ---------------------------------------------------------------------------
extern "C" void kernel_launch(void* const* d_in, const int* in_sizes, int n_in,
                              void* d_out, int out_size, void* d_ws, size_t ws_size,
                              hipStream_t stream)
{
    (void)n_in; (void)out_size; (void)ws_size;
    constexpr int NN = 204800, NCOMP = 8192, NGRAPH = 4096;

    const float* x    = (const float*)d_in[0];
    const float* w0a  = (const float*)d_in[1];
    const float* b0a  = (const float*)d_in[2];
    const float* w0b  = (const float*)d_in[3];
    const float* b0b  = (const float*)d_in[4];
    const float* wra  = (const float*)d_in[5];
    const float* bra  = (const float*)d_in[6];
    const float* wrb  = (const float*)d_in[7];
    const float* brb  = (const float*)d_in[8];
    const float* Wc   = (const float*)d_in[9];
    const float* f1w  = (const float*)d_in[10];
    const float* f1b  = (const float*)d_in[11];
    const float* bng  = (const float*)d_in[12];
    const float* bnb  = (const float*)d_in[13];
    const float* f2w  = (const float*)d_in[14];
    const float* f2bb = (const float*)d_in[15];
    const int* ei   = (const int*)d_in[16];
    const int  E    = in_sizes[16] / 2;           // 409600
    const int* src  = ei;
    const int* dst  = ei + E;

    // ---- workspace layout (~205 MiB) ----
    char* ws = (char*)d_ws;
    u16*    AEFF = (u16*)ws;                                 // [N,256] bf16, 100 MiB
    u16*    H   = (u16*)(ws + (size_t)104857600);            // [N,256] bf16, 100 MiB
    u16*    wt  = (u16*)(ws + (size_t)209715200);            // transposed bf16 weights, 1 MiB
    u16 *WT0 = wt, *WT1 = wt + 65536, *WT2 = wt + 131072, *WT3 = wt + 196608,
        *WT4 = wt + 262144, *WT5 = wt + 327680, *WT6 = wt + 393216;
    // CSR arrays after weights:
    char* csr = ws + (size_t)210763776;
    int* cnt    = (int*)csr;                                 // [N]
    int* rowptr = (int*)(csr + 819200);                      // [N]
    int* cursor = (int*)(csr + 1638400);                     // [N]
    int* col    = (int*)(csr + 2457600);                     // [E]
    int* bsum   = (int*)(csr + 4096000);                     // [1024]
    int* bscan  = (int*)(csr + 4100096);                     // [1024]
    // head scratch reuses dead AEFF region:
    u16*   Xc    = (u16*)ws;                                 // [8192,256] bf16
    float* Tfull = (float*)(ws + (size_t)16777216);          // [8192,512] f32
    float* Tp    = (float*)(ws + (size_t)33554432);          // [4096,64]
    float* T1    = (float*)(ws + (size_t)41943040);          // [4096,32]
    float* stats = (float*)(ws + (size_t)46137344);          // mu[32], rstd[32]

    const dim3 blk(256);
    const int NB = NN / 256;                                  // 800 scan blocks

    // ---- CSR build (once, reused by all 3 layers) ----
    hipMemsetAsync(cnt, 0, NN * 4, stream);
    k_count<<<(E + 255) / 256, blk, 0, stream>>>(dst, cnt, E);
    k_scan1<<<NB, blk, 0, stream>>>(cnt, rowptr, bsum, NN);
    k_scan2<<<1, blk, 0, stream>>>(bsum, bscan, NB);
    k_scan3<<<NB, blk, 0, stream>>>(rowptr, bscan, cursor, NN);
    k_fill<<<(E + 255) / 256, blk, 0, stream>>>(src, dst, cursor, col, E);

    // ---- pre-transpose weights (f32 -> bf16) ----
    k_T<<<128, blk, 0, stream>>>(w0a, WT0, 128, 256);
    k_T<<<256, blk, 0, stream>>>(w0b, WT1, 256, 256);
    k_T<<<256, blk, 0, stream>>>(wra,          WT2, 256, 256);
    k_T<<<256, blk, 0, stream>>>(wra + 65536,  WT3, 256, 256);
    k_T<<<256, blk, 0, stream>>>(wrb,          WT4, 256, 256);
    k_T<<<256, blk, 0, stream>>>(wrb + 65536,  WT5, 256, 256);
    k_T<<<512, blk, 0, stream>>>(Wc, WT6, 256, 512);

    // ---- layer 0 (K=128, src = x f32, no relu) ----
    k_aggr<128, false, true><<<(NN * 16) / 256, blk, 0, stream>>>(x, cnt, rowptr, col, AEFF, NN);
    k_gin<128><<<NN / 64, blk, 0, stream>>>(AEFF, WT0, b0a, WT1, b0b, H);

    // ---- layers 1..2 (K=256, src = H bf16, relu) ----
    const u16* WA[2] = {WT2, WT3};
    const u16* WB[2] = {WT4, WT5};
    for (int l = 0; l < 2; ++l) {
        k_aggr<256, true, false><<<(NN * 32) / 256, blk, 0, stream>>>(H, cnt, rowptr, col, AEFF, NN);
        k_gin<256><<<NN / 64, blk, 0, stream>>>(
            AEFF, WA[l], bra + (size_t)l * 256, WB[l], brb + (size_t)l * 256, H);
    }

    // ---- head ----
    k_pool<<<NCOMP, blk, 0, stream>>>(H, Xc);
    k_lin<<<dim3(NCOMP / 64, 2), blk, 0, stream>>>(Xc, WT6, Tfull);
    k_setpool<<<(NGRAPH * 64) / 256, blk, 0, stream>>>(Tfull, Tp);
    k_fc1<<<(NGRAPH * 32) / 256, blk, 0, stream>>>(Tp, f1w, f1b, T1);
    k_bnstats<<<32, blk, 0, stream>>>(T1, stats);
    k_head<<<NGRAPH / 256, blk, 0, stream>>>(T1, stats, bng, bnb, f2w, f2bb, (float*)d_out);
}